// Round 3
// baseline (132.887 us; speedup 1.0000x reference)
//
#include <hip/hip_runtime.h>

// YOLO loss: S=28, B=2, NUM_CLASSES=20, L_COORD=5, L_NOOBJ=0.5, N=1024
// Inputs (fp32 unless noted):
//   d_in[0] pred_tensor  (N,28,28,30)
//   d_in[1] target_boxes (N,28,28,4)
//   d_in[2] target_cls   (N,28,28,20)
//   d_in[3] has_object_map (N,28,28) bool -> int32 on device
// Output: 5 floats [total, reg, contain, noobj, cls]
//
// R3: single fused kernel. R2 showed the streaming part at ~5.9 TB/s
// (~94% of achievable); the remaining cost is the 2nd launch + gap.
// Last-block-done ticket (counter zeroed by a 4B memsetAsync each call,
// so replay-deterministic) lets the final 3136x4 partial reduce run in
// the tail of the same dispatch.
// ws layout: [0..63] header (counter at ws[0]); partials from ws+64.

__device__ inline float wave_reduce(float v) {
    #pragma unroll
    for (int off = 32; off > 0; off >>= 1)
        v += __shfl_down(v, off, 64);
    return v;
}

__global__ void __launch_bounds__(256) yolo_fused(
    const float* __restrict__ pred,
    const float* __restrict__ tbox,
    const float* __restrict__ tcls,
    const int*  __restrict__ mask,
    int*   __restrict__ counter,    // d_ws[0], zeroed each call
    float* __restrict__ partial,    // d_ws + 64 floats, gridDim.x * 4
    float* __restrict__ out,
    int ncells)
{
    __shared__ float sp[7680];              // 256 cells x 30 floats
    __shared__ float red[4][4];
    __shared__ int s_ticket;
    const float inv_s = 1.0f / 28.0f;

    float s_cls = 0.f, s_noobj = 0.f, s_contain = 0.f, s_reg = 0.f;

    const int nchunks = (ncells + 255) >> 8;
    for (int chunk = blockIdx.x; chunk < nchunks; chunk += gridDim.x) {
        const int base = chunk << 8;
        const int nc = min(256, ncells - base);

        __syncthreads();                    // protect LDS reuse (no-op first iter)
        if (nc == 256) {
            const float4* g4 = (const float4*)pred + (size_t)chunk * 1920;
            float4* s4 = (float4*)sp;
            #pragma unroll
            for (int i = 0; i < 8; ++i) {
                int idx = threadIdx.x + i * 256;
                if (idx < 1920) s4[idx] = g4[idx];
            }
        } else {
            for (int w = threadIdx.x; w < nc * 30; w += 256)
                sp[w] = pred[(size_t)base * 30 + w];
        }
        __syncthreads();

        const int cell = base + threadIdx.x;
        if (threadIdx.x < nc) {
            const float2* p2 = (const float2*)(sp + threadIdx.x * 30);
            float2 v0 = p2[0], v1 = p2[1], v2 = p2[2], v3 = p2[3], v4 = p2[4];
            // box0 = (v0.x, v0.y, v1.x, v1.y, conf v2.x)
            // box1 = (v2.y, v3.x, v3.y, v4.x, conf v4.y)

            float m = mask[cell] ? 1.0f : 0.0f;

            // ---- class loss
            float pc[20];
            #pragma unroll
            for (int k = 0; k < 10; k++) { float2 t = p2[5 + k]; pc[2*k] = t.x; pc[2*k+1] = t.y; }
            const float4* c4 = (const float4*)tcls + (size_t)cell * 5;
            float cl = 0.f;
            #pragma unroll
            for (int k = 0; k < 5; k++) {
                float4 t = c4[k];
                float d0 = pc[4*k+0] - t.x, d1 = pc[4*k+1] - t.y;
                float d2 = pc[4*k+2] - t.z, d3 = pc[4*k+3] - t.w;
                cl += d0*d0 + d1*d1 + d2*d2 + d3*d3;
            }
            s_cls += cl * m;

            // ---- no-object loss (x0.5 at the end)
            float conf0 = v2.x, conf1 = v4.y;
            s_noobj += (conf0*conf0 + conf1*conf1) * (1.0f - m);

            // ---- target box -> xyxy
            float4 tb = ((const float4*)tbox)[cell];
            float tx = tb.x * inv_s, ty = tb.y * inv_s;
            float tx1 = tx - 0.5f*tb.z, ty1 = ty - 0.5f*tb.w;
            float tx2 = tx + 0.5f*tb.z, ty2 = ty + 0.5f*tb.w;
            float area_t = (tx2 - tx1) * (ty2 - ty1);

            // ---- IoU of both pred boxes vs target
            float bxv[2] = {v0.x, v2.y}, byv[2] = {v0.y, v3.x};
            float bwv[2] = {v1.x, v3.y}, bhv[2] = {v1.y, v4.x};
            float confv[2] = {conf0, conf1};
            float iou[2];
            #pragma unroll
            for (int b = 0; b < 2; b++) {
                float px = bxv[b] * inv_s, py = byv[b] * inv_s;
                float px1 = px - 0.5f*bwv[b], py1 = py - 0.5f*bhv[b];
                float px2 = px + 0.5f*bwv[b], py2 = py + 0.5f*bhv[b];
                float ltx = fmaxf(px1, tx1), lty = fmaxf(py1, ty1);
                float rbx = fminf(px2, tx2), rby = fminf(py2, ty2);
                float w = fmaxf(rbx - ltx, 0.f), h = fmaxf(rby - lty, 0.f);
                float inter = w * h;
                float area_p = (px2 - px1) * (py2 - py1);
                iou[b] = inter / (area_p + area_t - inter);
            }
            int bi = (iou[1] > iou[0]) ? 1 : 0;   // argmax: first on ties
            float biou = fmaxf(iou[0], iou[1]);

            float bbx = bxv[bi], bby = byv[bi], bbw = bwv[bi], bbh = bhv[bi], bconf = confv[bi];

            // ---- regression loss (x5 at the end)
            float dx = bbx - tb.x, dy = bby - tb.y;
            float center = dx*dx + dy*dy;
            float sw = sqrtf(fmaxf(bbw, 0.f)) - sqrtf(tb.z);
            float sh = sqrtf(fmaxf(bbh, 0.f)) - sqrtf(tb.w);
            s_reg += (center + sw*sw + sh*sh) * m;

            // ---- containment loss
            float dc = bconf - biou;
            s_contain += dc * dc * m;
        }
    }

    // ---- block reduce: 4 waves x 4 sums
    int lane = threadIdx.x & 63, wid = threadIdx.x >> 6;
    s_cls = wave_reduce(s_cls);
    s_noobj = wave_reduce(s_noobj);
    s_contain = wave_reduce(s_contain);
    s_reg = wave_reduce(s_reg);
    if (lane == 0) {
        red[wid][0] = s_cls; red[wid][1] = s_noobj;
        red[wid][2] = s_contain; red[wid][3] = s_reg;
    }
    __syncthreads();
    if (threadIdx.x < 4) {
        float acc = red[0][threadIdx.x] + red[1][threadIdx.x]
                  + red[2][threadIdx.x] + red[3][threadIdx.x];
        partial[(size_t)blockIdx.x * 4 + threadIdx.x] = acc;
        __threadfence();                    // make partials device-visible
    }
    __syncthreads();
    if (threadIdx.x == 0) s_ticket = atomicAdd(counter, 1);
    __syncthreads();

    if (s_ticket == (int)gridDim.x - 1) {
        // ---- last block: final reduce of gridDim.x float4 partials
        __threadfence();
        float a0 = 0.f, a1 = 0.f, a2 = 0.f, a3 = 0.f;
        const float4* p4 = (const float4*)partial;
        for (int i = threadIdx.x; i < (int)gridDim.x; i += 256) {
            float4 t = p4[i];
            a0 += t.x; a1 += t.y; a2 += t.z; a3 += t.w;
        }
        a0 = wave_reduce(a0); a1 = wave_reduce(a1);
        a2 = wave_reduce(a2); a3 = wave_reduce(a3);
        __syncthreads();                    // red[][] reuse
        if (lane == 0) { red[wid][0]=a0; red[wid][1]=a1; red[wid][2]=a2; red[wid][3]=a3; }
        __syncthreads();
        if (threadIdx.x == 0) {
            float cls = 0.f, noobj = 0.f, contain = 0.f, reg = 0.f;
            #pragma unroll
            for (int w = 0; w < 4; w++) {
                cls += red[w][0]; noobj += red[w][1];
                contain += red[w][2]; reg += red[w][3];
            }
            noobj *= 0.5f;   // L_NOOBJ
            reg   *= 5.0f;   // L_COORD
            float total = (cls + noobj + contain + reg) / 1024.0f;
            out[0] = total; out[1] = reg; out[2] = contain;
            out[3] = noobj; out[4] = cls;
        }
    }
}

extern "C" void kernel_launch(void* const* d_in, const int* in_sizes, int n_in,
                              void* d_out, int out_size, void* d_ws, size_t ws_size,
                              hipStream_t stream) {
    const float* pred = (const float*)d_in[0];
    const float* tbox = (const float*)d_in[1];
    const float* tcls = (const float*)d_in[2];
    const int*   mask = (const int*)d_in[3];

    int ncells = in_sizes[3];                 // N * S * S = 802816
    int nchunks = (ncells + 255) / 256;       // 3136
    int nblocks = nchunks;
    // cap by workspace: 64-float header + 4 floats per block
    int maxblocks = (int)((ws_size - 256) / (4 * sizeof(float)));
    if (nblocks > maxblocks) nblocks = maxblocks;
    if (nblocks < 1) nblocks = 1;

    int*   counter = (int*)d_ws;
    float* partial = (float*)d_ws + 64;

    hipMemsetAsync(counter, 0, sizeof(int), stream);   // replay-deterministic ticket
    yolo_fused<<<nblocks, 256, 0, stream>>>(
        pred, tbox, tcls, mask, counter, partial, (float*)d_out, ncells);
}

// Round 4
// 59.932 us; speedup vs baseline: 2.2173x; 2.2173x over previous
//
#include <hip/hip_runtime.h>

// YOLO loss: S=28, B=2, NUM_CLASSES=20, L_COORD=5, L_NOOBJ=0.5, N=1024
// Inputs (fp32 unless noted):
//   d_in[0] pred_tensor  (N,28,28,30)
//   d_in[1] target_boxes (N,28,28,4)
//   d_in[2] target_cls   (N,28,28,20)
//   d_in[3] has_object_map (N,28,28) bool -> int32 on device
// Output: 5 floats [total, reg, contain, noobj, cls]
//
// R4: fused single kernel, SECOND attempt. R3's __threadfence() (device-scope
// L2 writeback per block x 3136) collapsed HBM BW 1300->425 GB/s. This version
// has NO fences: cross-block results travel only through the atomic path
// (device-coherent by HW). Per block: 4 float atomicAdds into 32-way-spread
// slots, wave-local s_waitcnt vmcnt(0) (release), ticket atomicAdd; last
// block reads slots back with atomicAdd(addr, 0.f) (coherent read).
// ws: [0] int counter; ws+64: float acc[4][32]; all zeroed via memsetAsync.

__device__ inline float wave_reduce(float v) {
    #pragma unroll
    for (int off = 32; off > 0; off >>= 1)
        v += __shfl_down(v, off, 64);
    return v;
}

__global__ void __launch_bounds__(256) yolo_fused(
    const float* __restrict__ pred,
    const float* __restrict__ tbox,
    const float* __restrict__ tcls,
    const int*  __restrict__ mask,
    int*   __restrict__ counter,    // d_ws[0], zeroed each call
    float* __restrict__ acc,        // d_ws+64: 4 metrics x 32 slots, zeroed
    float* __restrict__ out,
    int ncells)
{
    __shared__ float sp[7680];              // 256 cells x 30 floats
    __shared__ float red[4][4];
    __shared__ int s_ticket;
    const float inv_s = 1.0f / 28.0f;

    float s_cls = 0.f, s_noobj = 0.f, s_contain = 0.f, s_reg = 0.f;

    const int nchunks = (ncells + 255) >> 8;
    for (int chunk = blockIdx.x; chunk < nchunks; chunk += gridDim.x) {
        const int base = chunk << 8;
        const int nc = min(256, ncells - base);

        __syncthreads();                    // LDS reuse guard (no-op 1st iter)
        if (nc == 256) {
            const float4* g4 = (const float4*)pred + (size_t)chunk * 1920;
            float4* s4 = (float4*)sp;
            #pragma unroll
            for (int i = 0; i < 8; ++i) {
                int idx = threadIdx.x + i * 256;
                if (idx < 1920) s4[idx] = g4[idx];
            }
        } else {
            for (int w = threadIdx.x; w < nc * 30; w += 256)
                sp[w] = pred[(size_t)base * 30 + w];
        }
        __syncthreads();

        const int cell = base + threadIdx.x;
        if (threadIdx.x < nc) {
            const float2* p2 = (const float2*)(sp + threadIdx.x * 30);
            float2 v0 = p2[0], v1 = p2[1], v2 = p2[2], v3 = p2[3], v4 = p2[4];
            // box0 = (v0.x, v0.y, v1.x, v1.y, conf v2.x)
            // box1 = (v2.y, v3.x, v3.y, v4.x, conf v4.y)

            float m = mask[cell] ? 1.0f : 0.0f;

            // ---- class loss
            float pc[20];
            #pragma unroll
            for (int k = 0; k < 10; k++) { float2 t = p2[5 + k]; pc[2*k] = t.x; pc[2*k+1] = t.y; }
            const float4* c4 = (const float4*)tcls + (size_t)cell * 5;
            float cl = 0.f;
            #pragma unroll
            for (int k = 0; k < 5; k++) {
                float4 t = c4[k];
                float d0 = pc[4*k+0] - t.x, d1 = pc[4*k+1] - t.y;
                float d2 = pc[4*k+2] - t.z, d3 = pc[4*k+3] - t.w;
                cl += d0*d0 + d1*d1 + d2*d2 + d3*d3;
            }
            s_cls += cl * m;

            // ---- no-object loss (x0.5 at the end)
            float conf0 = v2.x, conf1 = v4.y;
            s_noobj += (conf0*conf0 + conf1*conf1) * (1.0f - m);

            // ---- target box -> xyxy
            float4 tb = ((const float4*)tbox)[cell];
            float tx = tb.x * inv_s, ty = tb.y * inv_s;
            float tx1 = tx - 0.5f*tb.z, ty1 = ty - 0.5f*tb.w;
            float tx2 = tx + 0.5f*tb.z, ty2 = ty + 0.5f*tb.w;
            float area_t = (tx2 - tx1) * (ty2 - ty1);

            // ---- IoU of both pred boxes vs target
            float bxv[2] = {v0.x, v2.y}, byv[2] = {v0.y, v3.x};
            float bwv[2] = {v1.x, v3.y}, bhv[2] = {v1.y, v4.x};
            float confv[2] = {conf0, conf1};
            float iou[2];
            #pragma unroll
            for (int b = 0; b < 2; b++) {
                float px = bxv[b] * inv_s, py = byv[b] * inv_s;
                float px1 = px - 0.5f*bwv[b], py1 = py - 0.5f*bhv[b];
                float px2 = px + 0.5f*bwv[b], py2 = py + 0.5f*bhv[b];
                float ltx = fmaxf(px1, tx1), lty = fmaxf(py1, ty1);
                float rbx = fminf(px2, tx2), rby = fminf(py2, ty2);
                float w = fmaxf(rbx - ltx, 0.f), h = fmaxf(rby - lty, 0.f);
                float inter = w * h;
                float area_p = (px2 - px1) * (py2 - py1);
                iou[b] = inter / (area_p + area_t - inter);
            }
            int bi = (iou[1] > iou[0]) ? 1 : 0;   // argmax: first on ties
            float biou = fmaxf(iou[0], iou[1]);

            float bbx = bxv[bi], bby = byv[bi], bbw = bwv[bi], bbh = bhv[bi], bconf = confv[bi];

            // ---- regression loss (x5 at the end)
            float dx = bbx - tb.x, dy = bby - tb.y;
            float center = dx*dx + dy*dy;
            float sw = sqrtf(fmaxf(bbw, 0.f)) - sqrtf(tb.z);
            float sh = sqrtf(fmaxf(bbh, 0.f)) - sqrtf(tb.w);
            s_reg += (center + sw*sw + sh*sh) * m;

            // ---- containment loss
            float dc = bconf - biou;
            s_contain += dc * dc * m;
        }
    }

    // ---- block reduce: 4 waves x 4 sums
    int lane = threadIdx.x & 63, wid = threadIdx.x >> 6;
    s_cls = wave_reduce(s_cls);
    s_noobj = wave_reduce(s_noobj);
    s_contain = wave_reduce(s_contain);
    s_reg = wave_reduce(s_reg);
    if (lane == 0) {
        red[wid][0] = s_cls; red[wid][1] = s_noobj;
        red[wid][2] = s_contain; red[wid][3] = s_reg;
    }
    __syncthreads();

    // ---- per-block: 4 atomic adds into spread slots (wave 0, lanes 0..3)
    if (threadIdx.x < 4) {
        float a = red[0][threadIdx.x] + red[1][threadIdx.x]
                + red[2][threadIdx.x] + red[3][threadIdx.x];
        atomicAdd(&acc[threadIdx.x * 32 + (blockIdx.x & 31)], a);
    }
    // release within wave 0: adds complete before the ticket is published
    asm volatile("s_waitcnt vmcnt(0)" ::: "memory");
    if (threadIdx.x == 0) s_ticket = atomicAdd(counter, 1);
    __syncthreads();

    if (s_ticket == (int)gridDim.x - 1) {
        // ---- last block: coherent read of 128 slots via atomic path
        float v = 0.f;
        if (threadIdx.x < 128) v = atomicAdd(&acc[threadIdx.x], 0.0f);
        __shared__ float sred[128];
        if (threadIdx.x < 128) sred[threadIdx.x] = v;
        __syncthreads();
        if (threadIdx.x < 4) {
            float s = 0.f;
            #pragma unroll
            for (int k = 0; k < 32; k++) s += sred[threadIdx.x * 32 + k];
            red[0][threadIdx.x] = s;
        }
        __syncthreads();
        if (threadIdx.x == 0) {
            float cls     = red[0][0];
            float noobj   = red[0][1] * 0.5f;   // L_NOOBJ
            float contain = red[0][2];
            float reg     = red[0][3] * 5.0f;   // L_COORD
            float total = (cls + noobj + contain + reg) / 1024.0f;
            out[0] = total; out[1] = reg; out[2] = contain;
            out[3] = noobj; out[4] = cls;
        }
    }
}

extern "C" void kernel_launch(void* const* d_in, const int* in_sizes, int n_in,
                              void* d_out, int out_size, void* d_ws, size_t ws_size,
                              hipStream_t stream) {
    const float* pred = (const float*)d_in[0];
    const float* tbox = (const float*)d_in[1];
    const float* tcls = (const float*)d_in[2];
    const int*   mask = (const int*)d_in[3];

    int ncells = in_sizes[3];                 // N * S * S = 802816
    int nblocks = (ncells + 255) / 256;       // 3136

    int*   counter = (int*)d_ws;
    float* acc     = (float*)d_ws + 64;       // 4 x 32 slots

    // zero counter + accumulators (768 B) — replay-deterministic
    hipMemsetAsync(d_ws, 0, 768, stream);
    yolo_fused<<<nblocks, 256, 0, stream>>>(
        pred, tbox, tcls, mask, counter, acc, (float*)d_out, ncells);
}

// Round 5
// 58.277 us; speedup vs baseline: 2.2803x; 1.0284x over previous
//
#include <hip/hip_runtime.h>

// YOLO loss: S=28, B=2, NUM_CLASSES=20, L_COORD=5, L_NOOBJ=0.5, N=1024
// Inputs (fp32 unless noted):
//   d_in[0] pred_tensor  (N,28,28,30)
//   d_in[1] target_boxes (N,28,28,4)
//   d_in[2] target_cls   (N,28,28,20)
//   d_in[3] has_object_map (N,28,28) bool -> int32 on device
// Output: 5 floats [total, reg, contain, noobj, cls]
//
// R5: back to two kernels (fusion lost twice: R3 fence -> BW collapse,
// R4 atomic epilogue -> +24us). New streaming structure: TWO cells per
// thread so pred is perfectly float4-aligned (60 floats = 15 dwordx4),
// no LDS, no barriers, ~28 independent 16B loads in flight per thread.
// Wave's 15 pred loads cover a contiguous 15KB span -> L1 absorbs the
// intra-line re-hits, full line utilization.

__device__ inline float wave_reduce(float v) {
    #pragma unroll
    for (int off = 32; off > 0; off >>= 1)
        v += __shfl_down(v, off, 64);
    return v;
}

// f: 30 floats of one pred cell (register array, constant-indexed)
// c4: global pointer to this cell's 5 float4 of target_cls
// tb: target box, m: mask
__device__ inline void cell_loss(const float* f, const float4* __restrict__ c4,
                                 float4 tb, float m,
                                 float& s_cls, float& s_noobj,
                                 float& s_contain, float& s_reg)
{
    const float inv_s = 1.0f / 28.0f;

    // ---- class loss: f[10..29] vs tcls
    float cl = 0.f;
    #pragma unroll
    for (int k = 0; k < 5; k++) {
        float4 t = c4[k];
        float d0 = f[10 + 4*k + 0] - t.x, d1 = f[10 + 4*k + 1] - t.y;
        float d2 = f[10 + 4*k + 2] - t.z, d3 = f[10 + 4*k + 3] - t.w;
        cl += d0*d0 + d1*d1 + d2*d2 + d3*d3;
    }
    s_cls += cl * m;

    // ---- no-object loss (x0.5 at the end)
    float conf0 = f[4], conf1 = f[9];
    s_noobj += (conf0*conf0 + conf1*conf1) * (1.0f - m);

    // ---- target box -> xyxy
    float tx = tb.x * inv_s, ty = tb.y * inv_s;
    float tx1 = tx - 0.5f*tb.z, ty1 = ty - 0.5f*tb.w;
    float tx2 = tx + 0.5f*tb.z, ty2 = ty + 0.5f*tb.w;
    float area_t = (tx2 - tx1) * (ty2 - ty1);

    // ---- IoU of both pred boxes vs target
    float bxv[2] = {f[0], f[5]}, byv[2] = {f[1], f[6]};
    float bwv[2] = {f[2], f[7]}, bhv[2] = {f[3], f[8]};
    float confv[2] = {conf0, conf1};
    float iou[2];
    #pragma unroll
    for (int b = 0; b < 2; b++) {
        float px = bxv[b] * inv_s, py = byv[b] * inv_s;
        float px1 = px - 0.5f*bwv[b], py1 = py - 0.5f*bhv[b];
        float px2 = px + 0.5f*bwv[b], py2 = py + 0.5f*bhv[b];
        float ltx = fmaxf(px1, tx1), lty = fmaxf(py1, ty1);
        float rbx = fminf(px2, tx2), rby = fminf(py2, ty2);
        float w = fmaxf(rbx - ltx, 0.f), h = fmaxf(rby - lty, 0.f);
        float inter = w * h;
        float area_p = (px2 - px1) * (py2 - py1);
        iou[b] = inter / (area_p + area_t - inter);
    }
    int bi = (iou[1] > iou[0]) ? 1 : 0;     // argmax: first index on ties
    float biou = fmaxf(iou[0], iou[1]);

    float bbx = bxv[bi], bby = byv[bi], bbw = bwv[bi], bbh = bhv[bi], bconf = confv[bi];

    // ---- regression loss (x5 at the end)
    float dx = bbx - tb.x, dy = bby - tb.y;
    float center = dx*dx + dy*dy;
    float sw = sqrtf(fmaxf(bbw, 0.f)) - sqrtf(tb.z);
    float sh = sqrtf(fmaxf(bbh, 0.f)) - sqrtf(tb.w);
    s_reg += (center + sw*sw + sh*sh) * m;

    // ---- containment loss
    float dc = bconf - biou;
    s_contain += dc * dc * m;
}

__global__ void __launch_bounds__(256) yolo_partial(
    const float* __restrict__ pred,
    const float* __restrict__ tbox,
    const float* __restrict__ tcls,
    const int*  __restrict__ mask,
    float* __restrict__ partial, int ncells)
{
    float s_cls = 0.f, s_noobj = 0.f, s_contain = 0.f, s_reg = 0.f;

    const int npairs = ncells >> 1;             // ncells is even (802816)
    const int pair = blockIdx.x * 256 + threadIdx.x;

    if (pair < npairs) {
        const int c0 = pair * 2;

        // ---- pred: 60 floats = 15 float4, 16B-aligned, contiguous
        const float4* p4 = (const float4*)pred + (size_t)pair * 15;
        float f[60];
        #pragma unroll
        for (int i = 0; i < 15; i++) {
            float4 q = p4[i];
            f[4*i+0] = q.x; f[4*i+1] = q.y; f[4*i+2] = q.z; f[4*i+3] = q.w;
        }

        // ---- other inputs
        const float4* c4 = (const float4*)tcls + (size_t)pair * 10;
        const float4* tb4 = (const float4*)tbox;
        float4 tbA = tb4[c0], tbB = tb4[c0 + 1];
        int2 mm = ((const int2*)mask)[pair];
        float mA = mm.x ? 1.0f : 0.0f;
        float mB = mm.y ? 1.0f : 0.0f;

        cell_loss(f,      c4,     tbA, mA, s_cls, s_noobj, s_contain, s_reg);
        cell_loss(f + 30, c4 + 5, tbB, mB, s_cls, s_noobj, s_contain, s_reg);
    }

    // ---- block reduce: 4 waves x 4 sums
    __shared__ float red[4][4];
    int lane = threadIdx.x & 63, wid = threadIdx.x >> 6;
    s_cls = wave_reduce(s_cls);
    s_noobj = wave_reduce(s_noobj);
    s_contain = wave_reduce(s_contain);
    s_reg = wave_reduce(s_reg);
    if (lane == 0) {
        red[wid][0] = s_cls; red[wid][1] = s_noobj;
        red[wid][2] = s_contain; red[wid][3] = s_reg;
    }
    __syncthreads();
    if (threadIdx.x < 4) {
        float acc = red[0][threadIdx.x] + red[1][threadIdx.x]
                  + red[2][threadIdx.x] + red[3][threadIdx.x];
        partial[(size_t)blockIdx.x * 4 + threadIdx.x] = acc;
    }
}

__global__ void __launch_bounds__(256) yolo_final(
    const float* __restrict__ partial, int nblocks, float* __restrict__ out)
{
    float s0 = 0.f, s1 = 0.f, s2 = 0.f, s3 = 0.f;
    const float4* p4 = (const float4*)partial;
    for (int i = threadIdx.x; i < nblocks; i += 256) {
        float4 t = p4[i];
        s0 += t.x; s1 += t.y; s2 += t.z; s3 += t.w;
    }
    __shared__ float red[4][4];
    int lane = threadIdx.x & 63, wid = threadIdx.x >> 6;
    s0 = wave_reduce(s0); s1 = wave_reduce(s1);
    s2 = wave_reduce(s2); s3 = wave_reduce(s3);
    if (lane == 0) { red[wid][0]=s0; red[wid][1]=s1; red[wid][2]=s2; red[wid][3]=s3; }
    __syncthreads();
    if (threadIdx.x == 0) {
        float cls = 0.f, noobj = 0.f, contain = 0.f, reg = 0.f;
        #pragma unroll
        for (int w = 0; w < 4; w++) {
            cls += red[w][0]; noobj += red[w][1];
            contain += red[w][2]; reg += red[w][3];
        }
        noobj *= 0.5f;   // L_NOOBJ
        reg   *= 5.0f;   // L_COORD
        float total = (cls + noobj + contain + reg) / 1024.0f;
        out[0] = total; out[1] = reg; out[2] = contain;
        out[3] = noobj; out[4] = cls;
    }
}

extern "C" void kernel_launch(void* const* d_in, const int* in_sizes, int n_in,
                              void* d_out, int out_size, void* d_ws, size_t ws_size,
                              hipStream_t stream) {
    const float* pred = (const float*)d_in[0];
    const float* tbox = (const float*)d_in[1];
    const float* tcls = (const float*)d_in[2];
    const int*   mask = (const int*)d_in[3];

    int ncells = in_sizes[3];                 // N * S * S = 802816 (even)
    int npairs = ncells >> 1;                 // 401408
    int nblocks = (npairs + 255) / 256;       // 1568
    int maxblocks = (int)(ws_size / (4 * sizeof(float)));
    if (nblocks > maxblocks) nblocks = maxblocks;
    if (nblocks < 1) nblocks = 1;

    yolo_partial<<<nblocks, 256, 0, stream>>>(
        pred, tbox, tcls, mask, (float*)d_ws, ncells);
    yolo_final<<<1, 256, 0, stream>>>((float*)d_ws, nblocks, (float*)d_out);
}

// Round 6
// 31.179 us; speedup vs baseline: 4.2621x; 1.8691x over previous
//
#include <hip/hip_runtime.h>

// YOLO loss: S=28, B=2, NUM_CLASSES=20, L_COORD=5, L_NOOBJ=0.5, N=1024
// Inputs (fp32 unless noted):
//   d_in[0] pred_tensor  (N,28,28,30)
//   d_in[1] target_boxes (N,28,28,4)
//   d_in[2] target_cls   (N,28,28,20)
//   d_in[3] has_object_map (N,28,28) bool -> int32 on device
// Output: 5 floats [total, reg, contain, noobj, cls]
//
// R6 = R2 skeleton (best: 35.5us; fusion R3/R4 and pairing R5 all lost)
// + mask predication: only the noobj term is live where mask==0 (75% of
// cells), and it needs just conf0/conf1 from LDS. tcls load (45% of all
// logical traffic), tbox load, IoU/sqrt/div chain, and 12/15 LDS reads
// are skipped under exec mask for those lanes.

__device__ inline float wave_reduce(float v) {
    #pragma unroll
    for (int off = 32; off > 0; off >>= 1)
        v += __shfl_down(v, off, 64);
    return v;
}

__global__ void __launch_bounds__(256) yolo_partial(
    const float* __restrict__ pred,
    const float* __restrict__ tbox,
    const float* __restrict__ tcls,
    const int*  __restrict__ mask,
    float* __restrict__ partial, int ncells)
{
    __shared__ float sp[7680];              // 256 cells x 30 floats = 30720 B
    const float inv_s = 1.0f / 28.0f;

    const int base = blockIdx.x * 256;
    const int nc   = min(256, ncells - base);

    // ---- stage pred chunk into LDS, fully coalesced ----
    if (nc == 256) {
        const float4* g4 = (const float4*)pred + (size_t)blockIdx.x * 1920;
        float4* s4 = (float4*)sp;
        #pragma unroll
        for (int i = 0; i < 8; ++i) {
            int idx = threadIdx.x + i * 256;
            if (idx < 1920) s4[idx] = g4[idx];
        }
    } else {
        for (int w = threadIdx.x; w < nc * 30; w += 256)
            sp[w] = pred[(size_t)base * 30 + w];
    }
    __syncthreads();

    float s_cls = 0.f, s_noobj = 0.f, s_contain = 0.f, s_reg = 0.f;

    const int cell = base + threadIdx.x;
    if (threadIdx.x < nc) {
        const float2* p2 = (const float2*)(sp + threadIdx.x * 30);
        // conf words needed on BOTH paths
        float2 v2 = p2[2], v4 = p2[4];
        float conf0 = v2.x, conf1 = v4.y;

        if (mask[cell] == 0) {
            // ---- no-object path (75% of lanes): conf only
            s_noobj = conf0*conf0 + conf1*conf1;   // x0.5 at the end
        } else {
            // ---- object path (25% of lanes): everything else, m == 1
            float2 v0 = p2[0], v1 = p2[1], v3 = p2[3];
            // box0 = (v0.x, v0.y, v1.x, v1.y, conf0)
            // box1 = (v2.y, v3.x, v3.y, v4.x, conf1)

            // class loss
            float pc[20];
            #pragma unroll
            for (int k = 0; k < 10; k++) { float2 t = p2[5 + k]; pc[2*k] = t.x; pc[2*k+1] = t.y; }
            const float4* c4 = (const float4*)tcls + (size_t)cell * 5;
            float cl = 0.f;
            #pragma unroll
            for (int k = 0; k < 5; k++) {
                float4 t = c4[k];
                float d0 = pc[4*k+0] - t.x, d1 = pc[4*k+1] - t.y;
                float d2 = pc[4*k+2] - t.z, d3 = pc[4*k+3] - t.w;
                cl += d0*d0 + d1*d1 + d2*d2 + d3*d3;
            }
            s_cls = cl;

            // target box -> xyxy
            float4 tb = ((const float4*)tbox)[cell];
            float tx = tb.x * inv_s, ty = tb.y * inv_s;
            float tx1 = tx - 0.5f*tb.z, ty1 = ty - 0.5f*tb.w;
            float tx2 = tx + 0.5f*tb.z, ty2 = ty + 0.5f*tb.w;
            float area_t = (tx2 - tx1) * (ty2 - ty1);

            // IoU of both pred boxes vs target
            float bxv[2] = {v0.x, v2.y}, byv[2] = {v0.y, v3.x};
            float bwv[2] = {v1.x, v3.y}, bhv[2] = {v1.y, v4.x};
            float confv[2] = {conf0, conf1};
            float iou[2];
            #pragma unroll
            for (int b = 0; b < 2; b++) {
                float px = bxv[b] * inv_s, py = byv[b] * inv_s;
                float px1 = px - 0.5f*bwv[b], py1 = py - 0.5f*bhv[b];
                float px2 = px + 0.5f*bwv[b], py2 = py + 0.5f*bhv[b];
                float ltx = fmaxf(px1, tx1), lty = fmaxf(py1, ty1);
                float rbx = fminf(px2, tx2), rby = fminf(py2, ty2);
                float w = fmaxf(rbx - ltx, 0.f), h = fmaxf(rby - lty, 0.f);
                float inter = w * h;
                float area_p = (px2 - px1) * (py2 - py1);
                iou[b] = inter / (area_p + area_t - inter);
            }
            int bi = (iou[1] > iou[0]) ? 1 : 0;   // argmax: first on ties
            float biou = fmaxf(iou[0], iou[1]);

            float bbx = bxv[bi], bby = byv[bi], bbw = bwv[bi], bbh = bhv[bi], bconf = confv[bi];

            // regression loss (x5 at the end)
            float dx = bbx - tb.x, dy = bby - tb.y;
            float center = dx*dx + dy*dy;
            float sw = sqrtf(fmaxf(bbw, 0.f)) - sqrtf(tb.z);
            float sh = sqrtf(fmaxf(bbh, 0.f)) - sqrtf(tb.w);
            s_reg = center + sw*sw + sh*sh;

            // containment loss
            float dc = bconf - biou;
            s_contain = dc * dc;
        }
    }

    // ---- block reduce: 4 waves x 4 sums
    __shared__ float red[4][4];
    int lane = threadIdx.x & 63, wid = threadIdx.x >> 6;
    s_cls = wave_reduce(s_cls);
    s_noobj = wave_reduce(s_noobj);
    s_contain = wave_reduce(s_contain);
    s_reg = wave_reduce(s_reg);
    if (lane == 0) {
        red[wid][0] = s_cls; red[wid][1] = s_noobj;
        red[wid][2] = s_contain; red[wid][3] = s_reg;
    }
    __syncthreads();
    if (threadIdx.x < 4) {
        float acc = red[0][threadIdx.x] + red[1][threadIdx.x]
                  + red[2][threadIdx.x] + red[3][threadIdx.x];
        partial[(size_t)blockIdx.x * 4 + threadIdx.x] = acc;
    }
}

__global__ void __launch_bounds__(256) yolo_final(
    const float* __restrict__ partial, int nblocks, float* __restrict__ out)
{
    float s0 = 0.f, s1 = 0.f, s2 = 0.f, s3 = 0.f;
    const float4* p4 = (const float4*)partial;
    for (int i = threadIdx.x; i < nblocks; i += 256) {
        float4 t = p4[i];
        s0 += t.x; s1 += t.y; s2 += t.z; s3 += t.w;
    }
    __shared__ float red[4][4];
    int lane = threadIdx.x & 63, wid = threadIdx.x >> 6;
    s0 = wave_reduce(s0); s1 = wave_reduce(s1);
    s2 = wave_reduce(s2); s3 = wave_reduce(s3);
    if (lane == 0) { red[wid][0]=s0; red[wid][1]=s1; red[wid][2]=s2; red[wid][3]=s3; }
    __syncthreads();
    if (threadIdx.x == 0) {
        float cls = 0.f, noobj = 0.f, contain = 0.f, reg = 0.f;
        #pragma unroll
        for (int w = 0; w < 4; w++) {
            cls += red[w][0]; noobj += red[w][1];
            contain += red[w][2]; reg += red[w][3];
        }
        noobj *= 0.5f;   // L_NOOBJ
        reg   *= 5.0f;   // L_COORD
        float total = (cls + noobj + contain + reg) / 1024.0f;
        out[0] = total; out[1] = reg; out[2] = contain;
        out[3] = noobj; out[4] = cls;
    }
}

extern "C" void kernel_launch(void* const* d_in, const int* in_sizes, int n_in,
                              void* d_out, int out_size, void* d_ws, size_t ws_size,
                              hipStream_t stream) {
    const float* pred = (const float*)d_in[0];
    const float* tbox = (const float*)d_in[1];
    const float* tcls = (const float*)d_in[2];
    const int*   mask = (const int*)d_in[3];

    int ncells = in_sizes[3];                 // N * S * S = 802816
    int nblocks = (ncells + 255) / 256;       // 3136
    int maxblocks = (int)(ws_size / (4 * sizeof(float)));
    if (nblocks > maxblocks) nblocks = maxblocks;
    if (nblocks < 1) nblocks = 1;

    yolo_partial<<<nblocks, 256, 0, stream>>>(
        pred, tbox, tcls, mask, (float*)d_ws, ncells);
    yolo_final<<<1, 256, 0, stream>>>((float*)d_ws, nblocks, (float*)d_out);
}